// Round 5
// baseline (506.856 us; speedup 1.0000x reference)
//
#include <hip/hip_runtime.h>
#include <cstdint>
#include <cstddef>

// SwinBlock3D: LN1 -> roll(-1,-3,-3) -> window(2,7,7) attn (12 heads, rel-bias)
// -> proj + resid -> LN2 -> MLP(384->1536 gelu ->384) + resid.
// bf16 MFMA for all matmuls, fp32 LN/softmax/residuals.
// qkv stored with row stride 1280 (N padded to 5x256 for the 256^2 GEMM).

typedef __bf16 bf16x8 __attribute__((ext_vector_type(8)));
typedef __bf16 bf16x4 __attribute__((ext_vector_type(4)));
typedef float f32x4 __attribute__((ext_vector_type(4)));

#define DIM 384
#define QKV_LD 1280
#define HID 1536
#define NHEADS 12
#define NTOK 50176
#define NWIN 512

// async global->LDS, 16B per lane; LDS dest = wave-uniform base + lane*16
__device__ __forceinline__ void gload16(const void* g, void* s) {
  __builtin_amdgcn_global_load_lds(
      (const __attribute__((address_space(1))) void*)g,
      (__attribute__((address_space(3))) void*)s, 16, 0, 0);
}

// ---------------- prep kernels ----------------
__global__ __launch_bounds__(256) void build_tokmap_k(int* __restrict__ map) {
  int t = blockIdx.x * 256 + threadIdx.x;
  if (t >= NTOK) return;
  int win = t / 98, n = t - win * 98;
  int b = win >> 8, tw = (win >> 6) & 3, hw = (win >> 3) & 7, ww = win & 7;
  int dt = n / 49; int rem = n - dt * 49; int dh = rem / 7, dw = rem - dh * 7;
  int t0 = (tw * 2 + dt + 1) & 7;                 // roll by shift (1,3,3)
  int h0 = hw * 7 + dh + 3; if (h0 >= 56) h0 -= 56;
  int w0 = ww * 7 + dw + 3; if (w0 >= 56) w0 -= 56;
  map[t] = ((b * 8 + t0) * 56 + h0) * 56 + w0;    // spatial row for window-token t
}

// packed bias in MFMA-fragment order: pb[h][mi][ni][lane][r], j>=98 mask pre-baked
__global__ __launch_bounds__(256) void expand_biasp_k(const float* __restrict__ table,
                                                      const int* __restrict__ rel,
                                                      float* __restrict__ out) {
  int e = blockIdx.x * 256 + threadIdx.x;
  if (e >= NHEADS * 49 * 256) return;
  int r = e & 3, l = (e >> 2) & 63;
  int rest = e >> 8;
  int ni = rest % 7, mi = (rest / 7) % 7, h = rest / 49;
  int i = mi * 16 + (l >> 4) * 4 + r;
  int j = ni * 16 + (l & 15);
  float v;
  if (j >= 98) v = -1e30f;          // pad-column mask baked in
  else if (i >= 98) v = 0.f;
  else v = table[rel[i * 98 + j] * NHEADS + h];
  out[e] = v;
}

// WT[Npad][K] <- W[K][Nreal] (bf16), zero rows beyond Nreal, q-scale folded
__global__ __launch_bounds__(256) void transpose_w_k(const float* __restrict__ W,
                                                     __bf16* __restrict__ WT,
                                                     int K, int Nreal, int Npad,
                                                     int scaleCols, float scale) {
  int e = blockIdx.x * 256 + threadIdx.x;
  if (e >= K * Npad) return;
  int n = e / K, k = e - n * K;
  float v = 0.f;
  if (n < Nreal) {
    v = W[(size_t)k * Nreal + n];
    if (n < scaleCols) v *= scale;
  }
  WT[e] = (__bf16)v;
}

__global__ __launch_bounds__(256) void scale_bias_k(const float* __restrict__ b,
                                                    float* __restrict__ out,
                                                    int nreal, int ntot,
                                                    int scaleCols, float scale) {
  int e = blockIdx.x * 256 + threadIdx.x;
  if (e >= ntot) return;
  out[e] = (e < nreal) ? b[e] * (e < scaleCols ? scale : 1.0f) : 0.f;
}

// V^T: vt[(win*12+h)*32 + d][tok 0..127] bf16, zeros past tok 97
__global__ __launch_bounds__(384) void vtrans_k(const __bf16* __restrict__ qkv,
                                                __bf16* __restrict__ vt) {
  int win = blockIdx.x, t = threadIdx.x;          // t = h*32+d
  const __bf16* base = qkv + (size_t)win * 98 * QKV_LD + 768 + t;
  __bf16* orow = vt + ((size_t)win * 384 + t) * 128;
  #pragma unroll
  for (int c = 0; c < 16; ++c) {
    bf16x8 pk;
    #pragma unroll
    for (int e2 = 0; e2 < 8; ++e2) {
      int tok = c * 8 + e2;
      pk[e2] = (tok < 98) ? base[(size_t)tok * QKV_LD] : (__bf16)0.f;
    }
    *(bf16x8*)(orow + c * 8) = pk;
  }
}

// ---------------- layernorm (1 wave per token row of 384) ----------------
__global__ __launch_bounds__(256) void ln_k(const float* __restrict__ x,
                                            const float* __restrict__ g,
                                            const float* __restrict__ bta,
                                            __bf16* __restrict__ out,
                                            const int* __restrict__ map) {
  int w = threadIdx.x >> 6, l = threadIdx.x & 63;
  int tok = blockIdx.x * 4 + w;
  int src = map ? map[tok] : tok;
  const float* row = x + (size_t)src * DIM;
  float v[6]; float s = 0.f;
  #pragma unroll
  for (int j = 0; j < 6; ++j) { v[j] = row[l + 64 * j]; s += v[j]; }
  #pragma unroll
  for (int m = 1; m < 64; m <<= 1) s += __shfl_xor(s, m, 64);
  float mu = s * (1.f / DIM);
  float var = 0.f;
  #pragma unroll
  for (int j = 0; j < 6; ++j) { float d = v[j] - mu; var += d * d; }
  #pragma unroll
  for (int m = 1; m < 64; m <<= 1) var += __shfl_xor(var, m, 64);
  float rs = rsqrtf(var * (1.f / DIM) + 1e-5f);
  __bf16* orow = out + (size_t)tok * DIM;
  #pragma unroll
  for (int j = 0; j < 6; ++j) {
    int c = l + 64 * j;
    orow[c] = (__bf16)((v[j] - mu) * rs * g[c] + bta[c]);
  }
}

// ---------------- 256x256 bf16 MFMA GEMM, BK=64, 8 waves, phase-split -------
// Per-wave 128x64 output (wave grid 2Mx4N). 4 phases per K-tile, each:
//   {ds_read A-pair (+B all on ph0) | issue async stage of next tile |
//    raw s_barrier | setprio(1) 16x MFMA setprio(0)}
// Tile-entry s_waitcnt vmcnt(0) + s_barrier (stages issued >=2 phases earlier).
// Raw s_barrier everywhere: compiler never drains vmcnt mid-pipeline.
// XOR swizzle: pre-swizzled global source chunk, linear LDS dest, swz ds_read.
// Operands swapped in MFMA -> C^T fragments -> vectorized epilogue.
// EPI: 0 = +bias -> bf16     2 = +bias, fast-gelu -> bf16
template <int EPI>
__global__ __launch_bounds__(512, 2) void gemm256_k(const __bf16* __restrict__ A,
                                                    const __bf16* __restrict__ BT,
                                                    const float* __restrict__ bias,
                                                    int M, int N, int K,
                                                    __bf16* __restrict__ outb) {
  __shared__ __align__(1024) char lds[131072];    // 2 x (A 32K | B 32K)
  const int tid = threadIdx.x;
  const int l = tid & 63, w = tid >> 6;
  const int lr = l & 15, lg = l >> 4;
  const int wr = w >> 2, wc = w & 3;
  const int ntile = N >> 8;
  // bijective XCD swizzle (m204): works for any grid size
  const int nwg = gridDim.x, qd = nwg >> 3, rm = nwg & 7;
  const int xcd = blockIdx.x & 7;
  const int wgid = (xcd < rm ? xcd * (qd + 1) : rm * (qd + 1) + (xcd - rm) * qd)
                   + (blockIdx.x >> 3);
  const int bm = wgid / ntile, bn = wgid - bm * ntile;
  const int m0 = bm << 8, n0 = bn << 8;
  // staging: thread covers chunk ci = s*512+tid; row = s*64 + (tid>>3), pre-swz src
  const int ci3 = tid >> 3;
  const int sch8 = ((tid & 7) ^ (ci3 & 7)) << 3;
  const __bf16* pa = A + (size_t)(m0 + ci3) * K + sch8;
  const __bf16* pb = BT + (size_t)(n0 + ci3) * K + sch8;
  const int dbase = tid << 4;
  const int nk = K >> 6;
  // swizzled ds_read column offsets (row&7 == lr&7 for all frag rows)
  const int sw0 = ((lg) ^ (lr & 7)) << 4;
  const int sw1 = ((4 + lg) ^ (lr & 7)) << 4;

  // prologue: tile 0 -> buffer 0
  #pragma unroll
  for (int s = 0; s < 4; ++s) {
    gload16(pa + (size_t)(s * 64) * K, lds + s * 8192 + dbase);
    gload16(pb + (size_t)(s * 64) * K, lds + 32768 + s * 8192 + dbase);
  }

  f32x4 acc[8][4] = {};

#define LDA_(mm, sw) (*(const bf16x8*)(ab + (wr << 14) + ((mm) << 11) + (lr << 7) + (sw)))
#define MFMA_PAIR(M0, M1, X0, X1)                                                       \
  _Pragma("unroll")                                                                     \
  for (int kk = 0; kk < 2; ++kk) {                                                      \
    _Pragma("unroll")                                                                   \
    for (int n = 0; n < 4; ++n) {                                                       \
      acc[M0][n] = __builtin_amdgcn_mfma_f32_16x16x32_bf16(bfr[n][kk], X0[kk], acc[M0][n], 0, 0, 0); \
      acc[M1][n] = __builtin_amdgcn_mfma_f32_16x16x32_bf16(bfr[n][kk], X1[kk], acc[M1][n], 0, 0, 0); \
    }                                                                                   \
  }

  for (int t = 0; t < nk; ++t) {
    const char* ab = lds + ((t & 1) << 16);
    const char* bb = ab + 32768;
    char* nb = lds + (((t + 1) & 1) << 16);
    const size_t koff = (size_t)(t + 1) << 6;
    const bool pf = (t + 1 < nk);
    asm volatile("s_waitcnt vmcnt(0)" ::: "memory");   // tile-t DMA (all waves') done
    asm volatile("s_barrier" ::: "memory");
    // ---- phase 0: B-frags (whole tile) + A m0,m1; stage next A ----
    bf16x8 bfr[4][2];
    #pragma unroll
    for (int n = 0; n < 4; ++n) {
      bfr[n][0] = *(const bf16x8*)(bb + (wc << 13) + (n << 11) + (lr << 7) + sw0);
      bfr[n][1] = *(const bf16x8*)(bb + (wc << 13) + (n << 11) + (lr << 7) + sw1);
    }
    bf16x8 x0[2], x1[2];
    x0[0] = LDA_(0, sw0); x0[1] = LDA_(0, sw1);
    x1[0] = LDA_(1, sw0); x1[1] = LDA_(1, sw1);
    if (pf) {
      #pragma unroll
      for (int s = 0; s < 4; ++s)
        gload16(pa + (size_t)(s * 64) * K + koff, nb + s * 8192 + dbase);
    }
    asm volatile("s_barrier" ::: "memory");
    __builtin_amdgcn_s_setprio(1);
    MFMA_PAIR(0, 1, x0, x1)
    __builtin_amdgcn_s_setprio(0);
    // ---- phase 1: A m2,m3; stage next B ----
    x0[0] = LDA_(2, sw0); x0[1] = LDA_(2, sw1);
    x1[0] = LDA_(3, sw0); x1[1] = LDA_(3, sw1);
    if (pf) {
      #pragma unroll
      for (int s = 0; s < 4; ++s)
        gload16(pb + (size_t)(s * 64) * K + koff, nb + 32768 + s * 8192 + dbase);
    }
    asm volatile("s_barrier" ::: "memory");
    __builtin_amdgcn_s_setprio(1);
    MFMA_PAIR(2, 3, x0, x1)
    __builtin_amdgcn_s_setprio(0);
    // ---- phase 2: A m4,m5 ----
    x0[0] = LDA_(4, sw0); x0[1] = LDA_(4, sw1);
    x1[0] = LDA_(5, sw0); x1[1] = LDA_(5, sw1);
    asm volatile("s_barrier" ::: "memory");
    __builtin_amdgcn_s_setprio(1);
    MFMA_PAIR(4, 5, x0, x1)
    __builtin_amdgcn_s_setprio(0);
    // ---- phase 3: A m6,m7 ----
    x0[0] = LDA_(6, sw0); x0[1] = LDA_(6, sw1);
    x1[0] = LDA_(7, sw0); x1[1] = LDA_(7, sw1);
    asm volatile("s_barrier" ::: "memory");
    __builtin_amdgcn_s_setprio(1);
    MFMA_PAIR(6, 7, x0, x1)
    __builtin_amdgcn_s_setprio(0);
  }
#undef LDA_
#undef MFMA_PAIR

  // epilogue (C^T frags): row = m0+wr*128+m*16+lr, cols = n0+wc*64+n*16+lg*4..+3
  #pragma unroll
  for (int m = 0; m < 8; ++m) {
    const int grow = m0 + (wr << 7) + (m << 4) + lr;
    #pragma unroll
    for (int n = 0; n < 4; ++n) {
      const int gcol = n0 + (wc << 6) + (n << 4) + (lg << 2);
      f32x4 a = acc[m][n] + *(const f32x4*)(bias + gcol);
      bf16x4 c;
      if (EPI == 0) {
        #pragma unroll
        for (int r = 0; r < 4; ++r) c[r] = (__bf16)a[r];
      } else {
        #pragma unroll
        for (int r = 0; r < 4; ++r) {
          float vv = a[r];
          float y = vv * (1.0f + 0.044715f * vv * vv);
          c[r] = (__bf16)(vv / (1.0f + __expf(-1.5957691216057308f * y)));
        }
      }
      *(bf16x4*)(outb + (size_t)grow * N + gcol) = c;
    }
  }
}

// ---------------- 128x128 bf16 MFMA GEMM, BK=64, 4 waves (proj/fc2) ---------
// EPI: 1 = +bias, scatter via tokmap, +resid -> fp32   3 = +bias, +resid -> fp32
template <int EPI>
__global__ __launch_bounds__(256) void gemm_k(const __bf16* __restrict__ A,
                                              const __bf16* __restrict__ BT,
                                              const float* __restrict__ bias,
                                              int M, int N, int K,
                                              float* __restrict__ outf,
                                              const float* __restrict__ resid,
                                              const int* __restrict__ tokmap) {
  __shared__ __align__(1024) char lds[65536];     // 2 buffers x (A 16K | B 16K)
  const int tid = threadIdx.x;
  const int l = tid & 63, w = tid >> 6;
  const int lr = l & 15, lg = l >> 4;
  const int ntile = N >> 7;
  const int nwg8 = gridDim.x >> 3;
  const int bid = (blockIdx.x & 7) * nwg8 + (blockIdx.x >> 3);
  const int bm = bid / ntile, bn = bid - bm * ntile;
  const int m0 = bm << 7, n0 = bn << 7;
  const int wr = w >> 1, wc = w & 1;
  const int srow = l >> 3;
  const int sch = (l & 7) ^ srow;
  const __bf16* pa = A + (size_t)(m0 + w * 32 + srow) * K + sch * 8;
  const __bf16* pb = BT + (size_t)(n0 + w * 32 + srow) * K + sch * 8;
  const int doff = w * 4096;
  const int nk = K >> 6;

  #pragma unroll
  for (int i = 0; i < 4; ++i) {
    gload16(pa + (size_t)(i * 8) * K, lds + doff + i * 1024);
    gload16(pb + (size_t)(i * 8) * K, lds + 16384 + doff + i * 1024);
  }

  f32x4 acc[4][4] = {};
  for (int kt = 0; kt < nk; ++kt) {
    char* cur = lds + ((kt & 1) << 15);
    if (kt + 1 < nk) {
      char* nxt = lds + (((kt + 1) & 1) << 15);
      const size_t koff = (size_t)(kt + 1) << 6;
      #pragma unroll
      for (int i = 0; i < 4; ++i) {
        gload16(pa + (size_t)(i * 8) * K + koff, nxt + doff + i * 1024);
        gload16(pb + (size_t)(i * 8) * K + koff, nxt + 16384 + doff + i * 1024);
      }
      asm volatile("s_waitcnt vmcnt(8)" ::: "memory");
    } else {
      asm volatile("s_waitcnt vmcnt(0)" ::: "memory");
    }
    asm volatile("s_barrier" ::: "memory");
    #pragma unroll
    for (int kk = 0; kk < 2; ++kk) {
      bf16x8 af[4], bfv[4];
      const int ck = (kk << 2) + lg;
      #pragma unroll
      for (int m = 0; m < 4; ++m) {
        int r = (wr << 6) + (m << 4) + lr;
        af[m] = *(const bf16x8*)(cur + (r << 7) + ((ck ^ (r & 7)) << 4));
      }
      #pragma unroll
      for (int n = 0; n < 4; ++n) {
        int r = (wc << 6) + (n << 4) + lr;
        bfv[n] = *(const bf16x8*)(cur + 16384 + (r << 7) + ((ck ^ (r & 7)) << 4));
      }
      #pragma unroll
      for (int m = 0; m < 4; ++m)
        #pragma unroll
        for (int n = 0; n < 4; ++n)
          acc[m][n] = __builtin_amdgcn_mfma_f32_16x16x32_bf16(bfv[n], af[m], acc[m][n], 0, 0, 0);
    }
    asm volatile("s_barrier" ::: "memory");
  }

  #pragma unroll
  for (int m = 0; m < 4; ++m) {
    const int grow = m0 + (wr << 6) + (m << 4) + lr;
    #pragma unroll
    for (int n = 0; n < 4; ++n) {
      const int gcol = n0 + (wc << 6) + (n << 4) + (lg << 2);
      f32x4 a = acc[m][n] + *(const f32x4*)(bias + gcol);
      if (EPI == 1) {
        int dst = tokmap[grow];
        f32x4 rv = *(const f32x4*)(resid + (size_t)dst * DIM + gcol);
        *(f32x4*)(outf + (size_t)dst * DIM + gcol) = rv + a;
      } else {
        f32x4 rv = *(const f32x4*)(resid + (size_t)grow * N + gcol);
        *(f32x4*)(outf + (size_t)grow * N + gcol) = rv + a;
      }
    }
  }
}

// ---------------- window attention: 1 wave per (window, head, mi-tile) ------
__global__ __launch_bounds__(64) void attn_k(const __bf16* __restrict__ qkv,
                                             const __bf16* __restrict__ vt,
                                             const float* __restrict__ pb,
                                             __bf16* __restrict__ out) {
  __shared__ __align__(1024) char P[4096];
  const int l = threadIdx.x, lr = l & 15, lg = l >> 4;
  const int bid = blockIdx.x;
  const int xc = bid & 7, kk = bid >> 3;
  const int wh = (kk / 7) * 8 + xc, mi = kk % 7;
  const int win = wh / NHEADS, h = wh - win * NHEADS;
  const size_t wbase = (size_t)win * 98 * QKV_LD;
  const __bf16* qb = qkv + wbase + h * 32;
  const __bf16* kb = qb + 384;
  const bf16x8 z8 = {};
  const f32x4 fz = {};

  bf16x8 kf[7];
  #pragma unroll
  for (int ni = 0; ni < 7; ++ni) {
    int tok = ni * 16 + lr;
    kf[ni] = (tok < 98) ? *(const bf16x8*)(kb + (size_t)tok * QKV_LD + lg * 8) : z8;
  }
  int qt = mi * 16 + lr;
  bf16x8 qf = (qt < 98) ? *(const bf16x8*)(qb + (size_t)qt * QKV_LD + lg * 8) : z8;
  const f32x4* pbp = (const f32x4*)pb + (size_t)((h * 7 + mi) * 7) * 64 + l;
  f32x4 bv[7];
  #pragma unroll
  for (int ni = 0; ni < 7; ++ni) bv[ni] = pbp[ni * 64];

  f32x4 s[7];
  #pragma unroll
  for (int ni = 0; ni < 7; ++ni)
    s[ni] = __builtin_amdgcn_mfma_f32_16x16x32_bf16(qf, kf[ni], fz, 0, 0, 0);

  if (l < 32) {
    int row = l >> 1, c = 14 + (l & 1);
    *(f32x4*)(P + row * 256 + ((c ^ (row & 7)) << 4)) = fz;
  }

  #pragma unroll
  for (int r = 0; r < 4; ++r) {
    float mx = -1e30f;
    #pragma unroll
    for (int ni = 0; ni < 7; ++ni) {
      float vv = s[ni][r] + bv[ni][r];
      s[ni][r] = vv;
      mx = fmaxf(mx, vv);
    }
    #pragma unroll
    for (int m2 = 1; m2 < 16; m2 <<= 1) mx = fmaxf(mx, __shfl_xor(mx, m2, 64));
    float sum = 0.f;
    #pragma unroll
    for (int ni = 0; ni < 7; ++ni) { float p = __expf(s[ni][r] - mx); s[ni][r] = p; sum += p; }
    #pragma unroll
    for (int m2 = 1; m2 < 16; m2 <<= 1) sum += __shfl_xor(sum, m2, 64);
    float inv = 1.0f / sum;
    int il = lg * 4 + r;
    #pragma unroll
    for (int ni = 0; ni < 7; ++ni) {
      int j = ni * 16 + lr;
      *(__bf16*)(P + il * 256 + (((j >> 3) ^ (il & 7)) << 4) + ((j & 7) << 1)) =
          (__bf16)(s[ni][r] * inv);
    }
  }
  __syncthreads();

  bf16x8 pa[4];
  #pragma unroll
  for (int ks = 0; ks < 4; ++ks) {
    int ck = ks * 4 + lg;
    pa[ks] = *(const bf16x8*)(P + lr * 256 + ((ck ^ (lr & 7)) << 4));
  }
  const __bf16* vrow = vt + ((size_t)wh * 32) * 128;
  __bf16* ob = out + ((size_t)win * 98 + mi * 16) * DIM + h * 32;
  #pragma unroll
  for (int nf = 0; nf < 2; ++nf) {
    int d = nf * 16 + lr;
    f32x4 o = fz;
    #pragma unroll
    for (int ks = 0; ks < 4; ++ks) {
      bf16x8 vb = *(const bf16x8*)(vrow + (size_t)d * 128 + ks * 32 + lg * 8);
      o = __builtin_amdgcn_mfma_f32_16x16x32_bf16(pa[ks], vb, o, 0, 0, 0);
    }
    #pragma unroll
    for (int r = 0; r < 4; ++r) {
      int il = lg * 4 + r;
      if (mi * 16 + il < 98) ob[(size_t)il * DIM + nf * 16 + lr] = (__bf16)o[r];
    }
  }
}

// ---------------- launch ----------------
extern "C" void kernel_launch(void* const* d_in, const int* in_sizes, int n_in,
                              void* d_out, int out_size, void* d_ws, size_t ws_size,
                              hipStream_t stream) {
  const float* x      = (const float*)d_in[0];
  const float* n1g    = (const float*)d_in[1];
  const float* n1b    = (const float*)d_in[2];
  const float* qkv_w  = (const float*)d_in[3];
  const float* qkv_b  = (const float*)d_in[4];
  const float* proj_w = (const float*)d_in[5];
  const float* proj_b = (const float*)d_in[6];
  const float* btab   = (const float*)d_in[7];
  const float* n2g    = (const float*)d_in[8];
  const float* n2b    = (const float*)d_in[9];
  const float* fc1_w  = (const float*)d_in[10];
  const float* fc1_b  = (const float*)d_in[11];
  const float* fc2_w  = (const float*)d_in[12];
  const float* fc2_b  = (const float*)d_in[13];
  const int*   relidx = (const int*)d_in[14];
  float* outp = (float*)d_out;
  (void)in_sizes; (void)n_in; (void)out_size; (void)ws_size;

  char* ws = (char*)d_ws;
  size_t off = 0;
  auto alloc = [&](size_t bytes) {
    char* p = ws + off;
    off = (off + bytes + 255) & ~(size_t)255;
    return p;
  };
  int*    tokmap = (int*)alloc((size_t)NTOK * 4);
  float*  biasex = (float*)alloc((size_t)NHEADS * 49 * 256 * 4);
  __bf16* wqkvT  = (__bf16*)alloc((size_t)QKV_LD * DIM * 2);   // padded rows 1152..1279 = 0
  __bf16* wprojT = (__bf16*)alloc((size_t)DIM * DIM * 2);
  __bf16* wfc1T  = (__bf16*)alloc((size_t)HID * DIM * 2);
  __bf16* wfc2T  = (__bf16*)alloc((size_t)DIM * HID * 2);
  float*  qkvbS  = (float*)alloc((size_t)QKV_LD * 4);
  __bf16* tokens = (__bf16*)alloc((size_t)NTOK * DIM * 2);     // LN1 out / attn out / LN2 out
  __bf16* qkvbuf = (__bf16*)alloc((size_t)NTOK * HID * 2);     // qkv (ld 1280) then h1 (1536)
  __bf16* attnout = tokens;
  __bf16* h1 = qkvbuf;
  // vt (50.3MB) lives in d_out (77MB fp32) — proj overwrites d_out afterwards
  __bf16* vt = (__bf16*)d_out;

  const float scale = 0.17677669529663687f;  // 1/sqrt(32)

  build_tokmap_k<<<NTOK / 256, 256, 0, stream>>>(tokmap);
  expand_biasp_k<<<(NHEADS * 49 * 256) / 256, 256, 0, stream>>>(btab, relidx, biasex);
  transpose_w_k<<<(DIM * QKV_LD) / 256, 256, 0, stream>>>(qkv_w, wqkvT, DIM, 1152, QKV_LD, DIM, scale);
  transpose_w_k<<<(DIM * DIM) / 256, 256, 0, stream>>>(proj_w, wprojT, DIM, DIM, DIM, 0, 1.0f);
  transpose_w_k<<<(DIM * HID) / 256, 256, 0, stream>>>(fc1_w, wfc1T, DIM, HID, HID, 0, 1.0f);
  transpose_w_k<<<(HID * DIM) / 256, 256, 0, stream>>>(fc2_w, wfc2T, HID, DIM, DIM, 0, 1.0f);
  scale_bias_k<<<(QKV_LD + 255) / 256, 256, 0, stream>>>(qkv_b, qkvbS, 1152, QKV_LD, DIM, scale);

  ln_k<<<NTOK / 4, 256, 0, stream>>>(x, n1g, n1b, tokens, tokmap);
  gemm256_k<0><<<(NTOK / 256) * (QKV_LD / 256), 512, 0, stream>>>(
      tokens, wqkvT, qkvbS, NTOK, QKV_LD, DIM, qkvbuf);
  vtrans_k<<<NWIN, 384, 0, stream>>>(qkvbuf, vt);
  attn_k<<<NWIN * NHEADS * 7, 64, 0, stream>>>(qkvbuf, vt, biasex, attnout);
  gemm_k<1><<<(NTOK / 128) * (DIM / 128), 256, 0, stream>>>(
      attnout, wprojT, proj_b, NTOK, DIM, DIM, outp, x, tokmap);
  ln_k<<<NTOK / 4, 256, 0, stream>>>(outp, n2g, n2b, tokens, nullptr);
  gemm256_k<2><<<(NTOK / 256) * (HID / 256), 512, 0, stream>>>(
      tokens, wfc1T, fc1_b, NTOK, HID, DIM, h1);
  gemm_k<3><<<(NTOK / 128) * (DIM / 128), 256, 0, stream>>>(
      h1, wfc2T, fc2_b, NTOK, DIM, HID, outp, outp, nullptr);
}